// Round 1
// baseline (147.113 us; speedup 1.0000x reference)
//
#include <hip/hip_runtime.h>
#include <hip/hip_bf16.h>
#include <stdint.h>

// MinGRU: B=8, S=4096, I=512, H=512 (fp32 in/out)
// K0: cvt x,W -> bf16 ws ; K1: MFMA GEMM -> preact[32768,1024] fp32
// K2: per-chunk (A,B) summaries ; K3: scan chunk summaries ; K4: replay+write out

typedef __attribute__((ext_vector_type(8))) short short8;   // 8 bf16 = 4 VGPR
typedef __attribute__((ext_vector_type(4))) float f32x4;

#define AS1 __attribute__((address_space(1)))
#define AS3 __attribute__((address_space(3)))

__device__ inline void gload_lds16(const void* g, void* l) {
  __builtin_amdgcn_global_load_lds((AS1 uint32_t*)(g), (AS3 uint32_t*)(l), 16, 0, 0);
}

// ---------------- K0: fp32 -> bf16 ----------------
__global__ void cvt_f32_bf16(const float* __restrict__ src, ushort* __restrict__ dst, int n4) {
  int i = blockIdx.x * blockDim.x + threadIdx.x;
  int stride = gridDim.x * blockDim.x;
  for (; i < n4; i += stride) {
    float4 v = reinterpret_cast<const float4*>(src)[i];
    union { __hip_bfloat16 h; ushort u; } a, b, c, d;
    a.h = __float2bfloat16(v.x);
    b.h = __float2bfloat16(v.y);
    c.h = __float2bfloat16(v.z);
    d.h = __float2bfloat16(v.w);
    ushort4 o = make_ushort4(a.u, b.u, c.u, d.u);
    reinterpret_cast<ushort4*>(dst)[i] = o;
  }
}

// ---------------- K1: GEMM (x @ W^T) -> preact ----------------
// grid (256 m-tiles, 8 n-tiles), 256 thr. Tile 128x128, BK=64.
// LDS linear [128 rows][64 bf16]; 16B slots XOR-swizzled: slot' = slot ^ (row&7)
// (applied on the GLOBAL source during global_load_lds, and on ds_read).
__global__ __launch_bounds__(256) void gemm_preact(
    const ushort* __restrict__ xb,   // [32768,512] bf16
    const ushort* __restrict__ wzb,  // [512,512] bf16
    const ushort* __restrict__ whb,  // [512,512] bf16
    float* __restrict__ preact)      // [32768,1024] fp32
{
  __shared__ __align__(16) char smem[32768];
  char* As = smem;            // 16 KiB: 128 x 64 bf16
  char* Bs = smem + 16384;    // 16 KiB

  const int t  = threadIdx.x;
  const int w  = t >> 6;
  const int l  = t & 63;
  const int lm = l & 15;      // MFMA row/col within 16
  const int lk = l >> 4;      // 0..3 -> k-slot
  const int wm = w >> 1, wn = w & 1;      // 2x2 wave grid, 64x64 each
  const int m0 = blockIdx.x * 128;
  const ushort* Wb = (blockIdx.y < 4) ? wzb : whb;
  const int nloc0 = (blockIdx.y & 3) * 128;

  const int srow  = t >> 3;   // staging: 32 rows / issue
  const int sslot = t & 7;

  f32x4 acc[4][4];
  #pragma unroll
  for (int m = 0; m < 4; ++m)
    #pragma unroll
    for (int n = 0; n < 4; ++n)
      acc[m][n] = (f32x4){0.f, 0.f, 0.f, 0.f};

  for (int kt = 0; kt < 8; ++kt) {
    const int k0 = kt * 64;
    #pragma unroll
    for (int j = 0; j < 4; ++j) {           // A: 4 x 4KiB issues
      int row = j * 32 + srow;
      int gs  = sslot ^ (row & 7);
      const ushort* gp = xb + (size_t)(m0 + row) * 512 + k0 + gs * 8;
      gload_lds16(gp, As + j * 4096 + w * 1024);
    }
    #pragma unroll
    for (int j = 0; j < 4; ++j) {           // B: 4 x 4KiB issues
      int row = j * 32 + srow;
      int gs  = sslot ^ (row & 7);
      const ushort* gp = Wb + (size_t)(nloc0 + row) * 512 + k0 + gs * 8;
      gload_lds16(gp, Bs + j * 4096 + w * 1024);
    }
    __syncthreads();   // compiler drains vmcnt before barrier

    #pragma unroll
    for (int kk = 0; kk < 2; ++kk) {
      short8 af[4], bf[4];
      #pragma unroll
      for (int m = 0; m < 4; ++m) {
        int row = wm * 64 + m * 16 + lm;
        int col16 = kk * 4 + lk;
        int off = row * 128 + ((col16 ^ (lm & 7)) << 4);
        af[m] = *(const short8*)(As + off);
      }
      #pragma unroll
      for (int n = 0; n < 4; ++n) {
        int row = wn * 64 + n * 16 + lm;
        int col16 = kk * 4 + lk;
        int off = row * 128 + ((col16 ^ (lm & 7)) << 4);
        bf[n] = *(const short8*)(Bs + off);
      }
      #pragma unroll
      for (int m = 0; m < 4; ++m)
        #pragma unroll
        for (int n = 0; n < 4; ++n)
          acc[m][n] = __builtin_amdgcn_mfma_f32_16x16x32_bf16(af[m], bf[n], acc[m][n], 0, 0, 0);
    }
    __syncthreads();
  }

  // epilogue: C row = (l>>4)*4 + j, col = l&15  (m89-verified layout)
  const size_t c0 = (size_t)blockIdx.y * 128 + wn * 64;
  #pragma unroll
  for (int m = 0; m < 4; ++m) {
    #pragma unroll
    for (int j = 0; j < 4; ++j) {
      size_t grow = (size_t)(m0 + wm * 64 + m * 16 + lk * 4 + j);
      float* po = preact + grow * 1024 + c0 + lm;
      #pragma unroll
      for (int n = 0; n < 4; ++n) po[n * 16] = acc[m][n][j];
    }
  }
}

// ---------------- K2: per-chunk summaries ----------------
// C=128 chunks x T=32. thread -> (b,c,h); A = prod(1-z), B = local scan from 0.
__global__ void chunk_reduce(const float* __restrict__ preact,
                             const float* __restrict__ b_z, const float* __restrict__ b_h,
                             float* __restrict__ Ac, float* __restrict__ Bc)
{
  int tid = blockIdx.x * 256 + threadIdx.x;   // 524288 total
  int h = tid & 511;
  int c = (tid >> 9) & 127;
  int b = tid >> 16;
  float bzv = b_z[h], bhv = b_h[h];
  const float* p = preact + ((size_t)b * 4096 + c * 32) * 1024 + h;
  float A = 1.f, Bv = 0.f;
  #pragma unroll 4
  for (int tt = 0; tt < 32; ++tt) {
    float uz = p[0] + bzv;
    float uh = p[512] + bhv;
    float z = 1.f / (1.f + __expf(-uz));
    float a = 1.f - z;
    A *= a;
    Bv = a * Bv + z * uh;
    p += 1024;
  }
  size_t off = ((size_t)b * 128 + c) * 512 + h;
  Ac[off] = A;
  Bc[off] = Bv;
}

// ---------------- K3: sequential scan over chunk summaries ----------------
__global__ void chunk_scan(const float* __restrict__ Ac, const float* __restrict__ Bc,
                           const float* __restrict__ h0, float* __restrict__ Hinit)
{
  int tid = blockIdx.x * 256 + threadIdx.x;   // 4096 total
  int h = tid & 511;
  int b = tid >> 9;
  float hv = h0[b * 512 + h];
  #pragma unroll 8
  for (int c = 0; c < 128; ++c) {
    size_t off = ((size_t)b * 128 + c) * 512 + h;
    Hinit[off] = hv;                 // h entering chunk c
    hv = Ac[off] * hv + Bc[off];
  }
}

// ---------------- K4: replay each chunk from Hinit, write out ----------------
__global__ void scan_write(const float* __restrict__ preact,
                           const float* __restrict__ b_z, const float* __restrict__ b_h,
                           const float* __restrict__ Hinit,
                           float* __restrict__ out)
{
  int tid = blockIdx.x * 256 + threadIdx.x;
  int h = tid & 511;
  int c = (tid >> 9) & 127;
  int b = tid >> 16;
  float bzv = b_z[h], bhv = b_h[h];
  const float* p = preact + ((size_t)b * 4096 + c * 32) * 1024 + h;
  float* po = out + ((size_t)b * 4096 + c * 32) * 512 + h;
  float hv = Hinit[((size_t)b * 128 + c) * 512 + h];
  #pragma unroll 4
  for (int tt = 0; tt < 32; ++tt) {
    float uz = p[0] + bzv;
    float uh = p[512] + bhv;
    float z = 1.f / (1.f + __expf(-uz));
    hv = (1.f - z) * hv + z * uh;
    *po = hv;
    p += 1024;
    po += 512;
  }
}

extern "C" void kernel_launch(void* const* d_in, const int* in_sizes, int n_in,
                              void* d_out, int out_size, void* d_ws, size_t ws_size,
                              hipStream_t stream) {
  const float* x   = (const float*)d_in[0];
  const float* h0  = (const float*)d_in[1];
  const float* W_z = (const float*)d_in[2];
  const float* b_z = (const float*)d_in[3];
  const float* W_h = (const float*)d_in[4];
  const float* b_h = (const float*)d_in[5];
  float* out = (float*)d_out;

  char* ws = (char*)d_ws;
  ushort* xb     = (ushort*)(ws);                  // 33,554,432 B
  ushort* wzb    = (ushort*)(ws + 33554432);       //    524,288 B
  ushort* whb    = (ushort*)(ws + 34078720);       //    524,288 B
  float*  preact = (float*) (ws + 34603008);       // 134,217,728 B
  float*  Ac     = (float*) (ws + 168820736);      //  2,097,152 B
  float*  Bc     = (float*) (ws + 170917888);      //  2,097,152 B
  float*  Hinit  = (float*) (ws + 173015040);      //  2,097,152 B  (end: 175,112,192)

  cvt_f32_bf16<<<2048, 256, 0, stream>>>(x,   xb,  16777216 / 4);
  cvt_f32_bf16<<<256,  256, 0, stream>>>(W_z, wzb, 262144 / 4);
  cvt_f32_bf16<<<256,  256, 0, stream>>>(W_h, whb, 262144 / 4);
  gemm_preact<<<dim3(256, 8), 256, 0, stream>>>(xb, wzb, whb, preact);
  chunk_reduce<<<2048, 256, 0, stream>>>(preact, b_z, b_h, Ac, Bc);
  chunk_scan<<<16, 256, 0, stream>>>(Ac, Bc, h0, Hinit);
  scan_write<<<2048, 256, 0, stream>>>(preact, b_z, b_h, Hinit, out);
}

// Round 2
// 135.985 us; speedup vs baseline: 1.0818x; 1.0818x over previous
//
#include <hip/hip_runtime.h>
#include <hip/hip_bf16.h>
#include <stdint.h>

// MinGRU: B=8, S=4096, I=512, H=512 (fp32 in/out)
// R1: merged z/h-gemm with fused gate epilogue -> packed bf16 (a,b) pairs.
// K0: cvt x,Wz,Wh -> bf16 (one launch)
// K1: gemm_gate -> ab[32768][512] uint (lo=bf16 a=1-z, hi=bf16 b=z*h~)
// K2: chunk_reduce -> per-chunk (A,B) float2
// K3: chunk_scan   -> Hinit per chunk
// K4: scan_write   -> out fp32

typedef __attribute__((ext_vector_type(8))) short short8;   // 8 bf16 = 4 VGPR
typedef __attribute__((ext_vector_type(4))) float f32x4;

#define AS1 __attribute__((address_space(1)))
#define AS3 __attribute__((address_space(3)))

__device__ inline void gload_lds16(const void* g, void* l) {
  __builtin_amdgcn_global_load_lds((AS1 uint32_t*)(g), (AS3 uint32_t*)(l), 16, 0, 0);
}

__device__ inline ushort f2bf(float f) {
  union { __hip_bfloat16 h; ushort u; } v;
  v.h = __float2bfloat16(f);
  return v.u;
}

// ---------------- K0: fp32 -> bf16 (x, W_z, W_h in one launch) ----------------
__global__ void cvt_all(const float* __restrict__ x,
                        const float* __restrict__ wz,
                        const float* __restrict__ wh,
                        ushort* __restrict__ xb,
                        ushort* __restrict__ wzb,
                        ushort* __restrict__ whb) {
  // float4 units: x 4194304, wz 65536, wh 65536 -> 4325376 total
  int i = blockIdx.x * 256 + threadIdx.x;
  for (; i < 4325376; i += 2048 * 256) {
    const float* s; ushort* d; int j;
    if (i < 4194304)      { s = x;  d = xb;  j = i; }
    else if (i < 4259840) { s = wz; d = wzb; j = i - 4194304; }
    else                  { s = wh; d = whb; j = i - 4259840; }
    float4 v = reinterpret_cast<const float4*>(s)[j];
    ushort4 o = make_ushort4(f2bf(v.x), f2bf(v.y), f2bf(v.z), f2bf(v.w));
    reinterpret_cast<ushort4*>(d)[j] = o;
  }
}

// ---------------- K1: merged GEMM + gate epilogue ----------------
// grid (256 m-tiles, 4 n-tiles), 256 thr (4 waves, 2x2 over 128x128).
// Each wave computes BOTH z and h~ 64x64 patches (shared A fragments).
// LDS: A 16K | Bz 16K | Bh 16K, 16B-slot XOR swizzle (slot ^= row&7) applied
// on the GLOBAL source for global_load_lds and on the ds_read address.
__global__ __launch_bounds__(256) void gemm_gate(
    const ushort* __restrict__ xb,   // [32768,512] bf16
    const ushort* __restrict__ wzb,  // [512,512] bf16
    const ushort* __restrict__ whb,  // [512,512] bf16
    const float* __restrict__ b_z,
    const float* __restrict__ b_h,
    uint* __restrict__ ab)           // [32768,512] packed (a,b) bf16
{
  __shared__ __align__(16) char smem[49152];
  char* As  = smem;            // 128 x 64 bf16
  char* Bzs = smem + 16384;
  char* Bhs = smem + 32768;

  const int t  = threadIdx.x;
  const int w  = t >> 6;
  const int l  = t & 63;
  const int lm = l & 15;
  const int lk = l >> 4;
  const int wm = w >> 1, wn = w & 1;       // 2x2 waves, 64x64 each
  const int m0 = blockIdx.x * 128;
  const int n0 = blockIdx.y * 128;

  const int srow  = t >> 3;    // 32 rows per 4KiB issue
  const int sslot = t & 7;

  // bias values for this lane's 4 n-columns
  float bzv[4], bhv[4];
  #pragma unroll
  for (int n = 0; n < 4; ++n) {
    int col = n0 + wn * 64 + n * 16 + lm;
    bzv[n] = b_z[col];
    bhv[n] = b_h[col];
  }

  f32x4 accz[4][4], acch[4][4];
  #pragma unroll
  for (int m = 0; m < 4; ++m)
    #pragma unroll
    for (int n = 0; n < 4; ++n) {
      accz[m][n] = (f32x4){0.f, 0.f, 0.f, 0.f};
      acch[m][n] = (f32x4){0.f, 0.f, 0.f, 0.f};
    }

  for (int kt = 0; kt < 8; ++kt) {
    const int k0 = kt * 64;
    #pragma unroll
    for (int j = 0; j < 4; ++j) {
      int row = j * 32 + srow;
      int gs  = sslot ^ (row & 7);
      gload_lds16(xb  + (size_t)(m0 + row) * 512 + k0 + gs * 8, As  + j * 4096 + w * 1024);
    }
    #pragma unroll
    for (int j = 0; j < 4; ++j) {
      int row = j * 32 + srow;
      int gs  = sslot ^ (row & 7);
      gload_lds16(wzb + (size_t)(n0 + row) * 512 + k0 + gs * 8, Bzs + j * 4096 + w * 1024);
    }
    #pragma unroll
    for (int j = 0; j < 4; ++j) {
      int row = j * 32 + srow;
      int gs  = sslot ^ (row & 7);
      gload_lds16(whb + (size_t)(n0 + row) * 512 + k0 + gs * 8, Bhs + j * 4096 + w * 1024);
    }
    __syncthreads();   // compiler drains vmcnt before barrier

    #pragma unroll
    for (int kk = 0; kk < 2; ++kk) {
      short8 af[4], bfz[4], bfh[4];
      const int col16 = kk * 4 + lk;
      const int soff  = ((col16 ^ (lm & 7)) << 4);
      #pragma unroll
      for (int m = 0; m < 4; ++m) {
        int row = wm * 64 + m * 16 + lm;
        af[m] = *(const short8*)(As + row * 128 + soff);
      }
      #pragma unroll
      for (int n = 0; n < 4; ++n) {
        int row = wn * 64 + n * 16 + lm;
        bfz[n] = *(const short8*)(Bzs + row * 128 + soff);
        bfh[n] = *(const short8*)(Bhs + row * 128 + soff);
      }
      #pragma unroll
      for (int m = 0; m < 4; ++m)
        #pragma unroll
        for (int n = 0; n < 4; ++n) {
          accz[m][n] = __builtin_amdgcn_mfma_f32_16x16x32_bf16(af[m], bfz[n], accz[m][n], 0, 0, 0);
          acch[m][n] = __builtin_amdgcn_mfma_f32_16x16x32_bf16(af[m], bfh[n], acch[m][n], 0, 0, 0);
        }
    }
    __syncthreads();
  }

  // epilogue: C row = lk*4 + j (within 16), col = lm (m89-verified layout)
  #pragma unroll
  for (int m = 0; m < 4; ++m) {
    #pragma unroll
    for (int j = 0; j < 4; ++j) {
      size_t grow = (size_t)(m0 + wm * 64 + m * 16 + lk * 4 + j);
      uint* po = ab + grow * 512 + n0 + wn * 64 + lm;
      #pragma unroll
      for (int n = 0; n < 4; ++n) {
        float uz = accz[m][n][j] + bzv[n];
        float uh = acch[m][n][j] + bhv[n];
        float z  = 1.f / (1.f + __expf(-uz));
        float a  = 1.f - z;
        float bb = z * uh;
        po[n * 16] = (uint)f2bf(a) | ((uint)f2bf(bb) << 16);
      }
    }
  }
}

// ---------------- K2: per-chunk summaries (C=128 chunks x T=32) ----------------
__global__ void chunk_reduce(const uint* __restrict__ ab,
                             float2* __restrict__ ABc)
{
  int tid = blockIdx.x * 256 + threadIdx.x;   // 524288 total
  int h = tid & 511;
  int c = (tid >> 9) & 127;
  int b = tid >> 16;
  const uint* p = ab + ((size_t)b * 4096 + c * 32) * 512 + h;
  float A = 1.f, Bv = 0.f;
  #pragma unroll 4
  for (int tt = 0; tt < 32; ++tt) {
    uint u = *p;
    float a  = __uint_as_float(u << 16);
    float bb = __uint_as_float(u & 0xffff0000u);
    A *= a;
    Bv = a * Bv + bb;
    p += 512;
  }
  ABc[((size_t)b * 128 + c) * 512 + h] = make_float2(A, Bv);
}

// ---------------- K3: sequential scan over chunk summaries ----------------
__global__ void chunk_scan(const float2* __restrict__ ABc,
                           const float* __restrict__ h0,
                           float* __restrict__ Hinit)
{
  int tid = blockIdx.x * 256 + threadIdx.x;   // 4096 total
  int h = tid & 511;
  int b = tid >> 9;
  float hv = h0[b * 512 + h];
  #pragma unroll 8
  for (int c = 0; c < 128; ++c) {
    size_t off = ((size_t)b * 128 + c) * 512 + h;
    Hinit[off] = hv;                 // h entering chunk c
    float2 s = ABc[off];
    hv = s.x * hv + s.y;
  }
}

// ---------------- K4: replay each chunk from Hinit, write out ----------------
__global__ void scan_write(const uint* __restrict__ ab,
                           const float* __restrict__ Hinit,
                           float* __restrict__ out)
{
  int tid = blockIdx.x * 256 + threadIdx.x;
  int h = tid & 511;
  int c = (tid >> 9) & 127;
  int b = tid >> 16;
  const uint* p = ab + ((size_t)b * 4096 + c * 32) * 512 + h;
  float* po = out + ((size_t)b * 4096 + c * 32) * 512 + h;
  float hv = Hinit[((size_t)b * 128 + c) * 512 + h];
  #pragma unroll 4
  for (int tt = 0; tt < 32; ++tt) {
    uint u = *p;
    float a  = __uint_as_float(u << 16);
    float bb = __uint_as_float(u & 0xffff0000u);
    hv = a * hv + bb;
    *po = hv;
    p += 512;
    po += 512;
  }
}

extern "C" void kernel_launch(void* const* d_in, const int* in_sizes, int n_in,
                              void* d_out, int out_size, void* d_ws, size_t ws_size,
                              hipStream_t stream) {
  const float* x   = (const float*)d_in[0];
  const float* h0  = (const float*)d_in[1];
  const float* W_z = (const float*)d_in[2];
  const float* b_z = (const float*)d_in[3];
  const float* W_h = (const float*)d_in[4];
  const float* b_h = (const float*)d_in[5];
  float* out = (float*)d_out;

  char* ws = (char*)d_ws;
  ushort* xb    = (ushort*)(ws);                  // 33,554,432 B
  ushort* wzb   = (ushort*)(ws + 33554432);       //    524,288 B
  ushort* whb   = (ushort*)(ws + 34078720);       //    524,288 B
  uint*   ab    = (uint*)  (ws + 34603008);       // 67,108,864 B
  float2* ABc   = (float2*)(ws + 101711872);      //  4,194,304 B
  float*  Hinit = (float*) (ws + 105906176);      //  2,097,152 B  (end: 108,003,328)

  cvt_all<<<2048, 256, 0, stream>>>(x, W_z, W_h, xb, wzb, whb);
  gemm_gate<<<dim3(256, 4), 256, 0, stream>>>(xb, wzb, whb, b_z, b_h, ab);
  chunk_reduce<<<2048, 256, 0, stream>>>(ab, ABc);
  chunk_scan<<<16, 256, 0, stream>>>(ABc, h0, Hinit);
  scan_write<<<2048, 256, 0, stream>>>(ab, Hinit, out);
}

// Round 3
// 127.547 us; speedup vs baseline: 1.1534x; 1.0662x over previous
//
#include <hip/hip_runtime.h>
#include <hip/hip_bf16.h>
#include <stdint.h>

// MinGRU: B=8, S=4096, I=512, H=512 (fp32 in/out)
// R2: gemm_gate -> 2-phase double-buffered pipeline (T3 minimum recipe),
//     grid restored to 2048 blocks (M-tile 128 x N-tile 64, both z & h).
// K0: cvt x,Wz,Wh -> bf16 ; K1: gemm_gate -> packed bf16 (a,b)
// K2: chunk_reduce ; K3: chunk_scan ; K4: scan_write

typedef __attribute__((ext_vector_type(8))) short short8;   // 8 bf16 = 4 VGPR
typedef __attribute__((ext_vector_type(4))) float f32x4;

#define AS1 __attribute__((address_space(1)))
#define AS3 __attribute__((address_space(3)))

__device__ inline void gload_lds16(const void* g, void* l) {
  __builtin_amdgcn_global_load_lds((AS1 uint32_t*)(g), (AS3 uint32_t*)(l), 16, 0, 0);
}

__device__ inline ushort f2bf(float f) {
  union { __hip_bfloat16 h; ushort u; } v;
  v.h = __float2bfloat16(f);
  return v.u;
}

// ---------------- K0: fp32 -> bf16 (x, W_z, W_h in one launch) ----------------
__global__ void cvt_all(const float* __restrict__ x,
                        const float* __restrict__ wz,
                        const float* __restrict__ wh,
                        ushort* __restrict__ xb,
                        ushort* __restrict__ wzb,
                        ushort* __restrict__ whb) {
  int i = blockIdx.x * 256 + threadIdx.x;
  for (; i < 4325376; i += 2048 * 256) {
    const float* s; ushort* d; int j;
    if (i < 4194304)      { s = x;  d = xb;  j = i; }
    else if (i < 4259840) { s = wz; d = wzb; j = i - 4194304; }
    else                  { s = wh; d = whb; j = i - 4259840; }
    float4 v = reinterpret_cast<const float4*>(s)[j];
    ushort4 o = make_ushort4(f2bf(v.x), f2bf(v.y), f2bf(v.z), f2bf(v.w));
    reinterpret_cast<ushort4*>(d)[j] = o;
  }
}

// ---------------- K1: merged GEMM + gate epilogue (2-phase pipeline) ----------
// grid (256, 8): m0 = bx*128, n0 = by*64. 4 waves 2x2 -> each wave 64x32 of
// BOTH z and h~. LDS: double-buffered A(16K) Bz(8K) Bh(8K) = 64 KiB.
// 16B-slot XOR swizzle (slot ^= row&7) on global source + ds_read address.
__global__ __launch_bounds__(256) void gemm_gate(
    const ushort* __restrict__ xb,   // [32768,512] bf16
    const ushort* __restrict__ wzb,  // [512,512] bf16
    const ushort* __restrict__ whb,  // [512,512] bf16
    const float* __restrict__ b_z,
    const float* __restrict__ b_h,
    uint* __restrict__ ab)           // [32768,512] packed (a,b) bf16
{
  __shared__ __align__(16) char smem[65536];
  // [0]A0 [16384]A1 [32768]Bz0 [40960]Bz1 [49152]Bh0 [57344]Bh1

  const int t  = threadIdx.x;
  const int w  = t >> 6;
  const int l  = t & 63;
  const int lm = l & 15;
  const int lk = l >> 4;
  const int wm = w >> 1, wn = w & 1;       // 2x2 waves: 64 rows x 32 cols each
  const int m0 = blockIdx.x * 128;
  const int n0 = blockIdx.y * 64;

  const int srow  = t >> 3;    // 32 rows per 4KiB issue
  const int sslot = t & 7;

  float bzv[2], bhv[2];
  #pragma unroll
  for (int n = 0; n < 2; ++n) {
    int col = n0 + wn * 32 + n * 16 + lm;
    bzv[n] = b_z[col];
    bhv[n] = b_h[col];
  }

  f32x4 accz[4][2], acch[4][2];
  #pragma unroll
  for (int m = 0; m < 4; ++m)
    #pragma unroll
    for (int n = 0; n < 2; ++n) {
      accz[m][n] = (f32x4){0.f, 0.f, 0.f, 0.f};
      acch[m][n] = (f32x4){0.f, 0.f, 0.f, 0.f};
    }

  auto stage = [&](int sel, int kt) {
    const int k0 = kt * 64;
    char* As  = smem + sel * 16384;
    char* Bzs = smem + 32768 + sel * 8192;
    char* Bhs = smem + 49152 + sel * 8192;
    #pragma unroll
    for (int j = 0; j < 4; ++j) {
      int row = j * 32 + srow;
      int gs  = sslot ^ (row & 7);
      gload_lds16(xb + (size_t)(m0 + row) * 512 + k0 + gs * 8, As + j * 4096 + w * 1024);
    }
    #pragma unroll
    for (int j = 0; j < 2; ++j) {
      int row = j * 32 + srow;
      int gs  = sslot ^ (row & 7);
      gload_lds16(wzb + (size_t)(n0 + row) * 512 + k0 + gs * 8, Bzs + j * 4096 + w * 1024);
      gload_lds16(whb + (size_t)(n0 + row) * 512 + k0 + gs * 8, Bhs + j * 4096 + w * 1024);
    }
  };

  stage(0, 0);
  __syncthreads();            // drain prologue staging

  int cur = 0;
  for (int kt = 0; kt < 8; ++kt) {
    if (kt < 7) stage(cur ^ 1, kt + 1);   // issue next tile BEFORE compute

    const char* As  = smem + cur * 16384;
    const char* Bzs = smem + 32768 + cur * 8192;
    const char* Bhs = smem + 49152 + cur * 8192;

    #pragma unroll
    for (int kk = 0; kk < 2; ++kk) {
      short8 af[4], bfz[2], bfh[2];
      const int soff = (((kk * 4 + lk) ^ (lm & 7)) << 4);
      #pragma unroll
      for (int m = 0; m < 4; ++m) {
        int row = wm * 64 + m * 16 + lm;
        af[m] = *(const short8*)(As + row * 128 + soff);
      }
      #pragma unroll
      for (int n = 0; n < 2; ++n) {
        int row = wn * 32 + n * 16 + lm;
        bfz[n] = *(const short8*)(Bzs + row * 128 + soff);
        bfh[n] = *(const short8*)(Bhs + row * 128 + soff);
      }
      #pragma unroll
      for (int m = 0; m < 4; ++m)
        #pragma unroll
        for (int n = 0; n < 2; ++n) {
          accz[m][n] = __builtin_amdgcn_mfma_f32_16x16x32_bf16(af[m], bfz[n], accz[m][n], 0, 0, 0);
          acch[m][n] = __builtin_amdgcn_mfma_f32_16x16x32_bf16(af[m], bfh[n], acch[m][n], 0, 0, 0);
        }
    }
    __syncthreads();          // drains next-tile vmcnt + protects buffer reuse
    cur ^= 1;
  }

  // epilogue: C row = lk*4 + j (within 16), col = lm (m89-verified layout)
  #pragma unroll
  for (int m = 0; m < 4; ++m) {
    #pragma unroll
    for (int j = 0; j < 4; ++j) {
      size_t grow = (size_t)(m0 + wm * 64 + m * 16 + lk * 4 + j);
      uint* po = ab + grow * 512 + n0 + wn * 32 + lm;
      #pragma unroll
      for (int n = 0; n < 2; ++n) {
        float uz = accz[m][n][j] + bzv[n];
        float uh = acch[m][n][j] + bhv[n];
        float z  = 1.f / (1.f + __expf(-uz));
        po[n * 16] = (uint)f2bf(1.f - z) | ((uint)f2bf(z * uh) << 16);
      }
    }
  }
}

// ---------------- K2: per-chunk summaries (C=128 chunks x T=32) ----------------
__global__ void chunk_reduce(const uint* __restrict__ ab,
                             float2* __restrict__ ABc)
{
  int tid = blockIdx.x * 256 + threadIdx.x;   // 524288 total
  int h = tid & 511;
  int c = (tid >> 9) & 127;
  int b = tid >> 16;
  const uint* p = ab + ((size_t)b * 4096 + c * 32) * 512 + h;
  float A = 1.f, Bv = 0.f;
  #pragma unroll 4
  for (int tt = 0; tt < 32; ++tt) {
    uint u = *p;
    float a  = __uint_as_float(u << 16);
    float bb = __uint_as_float(u & 0xffff0000u);
    A *= a;
    Bv = a * Bv + bb;
    p += 512;
  }
  ABc[((size_t)b * 128 + c) * 512 + h] = make_float2(A, Bv);
}

// ---------------- K3: sequential scan over chunk summaries ----------------
__global__ void chunk_scan(const float2* __restrict__ ABc,
                           const float* __restrict__ h0,
                           float* __restrict__ Hinit)
{
  int tid = blockIdx.x * 256 + threadIdx.x;   // 4096 total
  int h = tid & 511;
  int b = tid >> 9;
  float hv = h0[b * 512 + h];
  #pragma unroll 8
  for (int c = 0; c < 128; ++c) {
    size_t off = ((size_t)b * 128 + c) * 512 + h;
    Hinit[off] = hv;                 // h entering chunk c
    float2 s = ABc[off];
    hv = s.x * hv + s.y;
  }
}

// ---------------- K4: replay each chunk from Hinit, write out ----------------
__global__ void scan_write(const uint* __restrict__ ab,
                           const float* __restrict__ Hinit,
                           float* __restrict__ out)
{
  int tid = blockIdx.x * 256 + threadIdx.x;
  int h = tid & 511;
  int c = (tid >> 9) & 127;
  int b = tid >> 16;
  const uint* p = ab + ((size_t)b * 4096 + c * 32) * 512 + h;
  float* po = out + ((size_t)b * 4096 + c * 32) * 512 + h;
  float hv = Hinit[((size_t)b * 128 + c) * 512 + h];
  #pragma unroll 4
  for (int tt = 0; tt < 32; ++tt) {
    uint u = *p;
    float a  = __uint_as_float(u << 16);
    float bb = __uint_as_float(u & 0xffff0000u);
    hv = a * hv + bb;
    *po = hv;
    p += 512;
    po += 512;
  }
}

extern "C" void kernel_launch(void* const* d_in, const int* in_sizes, int n_in,
                              void* d_out, int out_size, void* d_ws, size_t ws_size,
                              hipStream_t stream) {
  const float* x   = (const float*)d_in[0];
  const float* h0  = (const float*)d_in[1];
  const float* W_z = (const float*)d_in[2];
  const float* b_z = (const float*)d_in[3];
  const float* W_h = (const float*)d_in[4];
  const float* b_h = (const float*)d_in[5];
  float* out = (float*)d_out;

  char* ws = (char*)d_ws;
  ushort* xb    = (ushort*)(ws);                  // 33,554,432 B
  ushort* wzb   = (ushort*)(ws + 33554432);       //    524,288 B
  ushort* whb   = (ushort*)(ws + 34078720);       //    524,288 B
  uint*   ab    = (uint*)  (ws + 34603008);       // 67,108,864 B
  float2* ABc   = (float2*)(ws + 101711872);      //  4,194,304 B
  float*  Hinit = (float*) (ws + 105906176);      //  2,097,152 B  (end: 108,003,328)

  cvt_all<<<2048, 256, 0, stream>>>(x, W_z, W_h, xb, wzb, whb);
  gemm_gate<<<dim3(256, 8), 256, 0, stream>>>(xb, wzb, whb, b_z, b_h, ab);
  chunk_reduce<<<2048, 256, 0, stream>>>(ab, ABc);
  chunk_scan<<<16, 256, 0, stream>>>(ABc, h0, Hinit);
  scan_write<<<2048, 256, 0, stream>>>(ab, Hinit, out);
}